// Round 2
// baseline (537.839 us; speedup 1.0000x reference)
//
#include <hip/hip_runtime.h>
#include <hip/hip_bf16.h>

// PixelContrastLossOnlyNeg on MI355X.
// feats [16,256,128,128] f32, queue [256,256] f32, labels [262144,256] i32 -> scalar f32.
// Fused bf16-MFMA GEMM (N=262144, M=256, K=256) + masked-exp reduction.
// Memory floor: feats 256MB + labels 256MB = 512MB -> ~81us @ 6.3TB/s.
//
// R2: B staged in LDS as bf16 in MFMA B-fragment order (one ds_read_b128 per
// (ks,nt) instead of 256 ds_read_b32 gathers + 4x-redundant packs); LDS
// 68.6->34.8 KB => 4 blocks/CU; single-exp epilogue; double-buffered label loads.

typedef __bf16 bf16x8 __attribute__((ext_vector_type(8)));
typedef float floatx4 __attribute__((ext_vector_type(4)));

// Pack two f32 -> two bf16 (round-half-up; bias ~2^-17 rel, irrelevant here).
__device__ __forceinline__ unsigned int pack_bf2(float a, float b) {
  unsigned int ua = __float_as_uint(a) + 0x8000u;
  unsigned int ub = __float_as_uint(b) + 0x8000u;
  return (ua >> 16) | (ub & 0xffff0000u);
}

// ---------------------------------------------------------------------------
// k0: queue f32 -> bf16 * (1/T), stored pre-swizzled in A-fragment lane order:
//   tile t = m16*8 + ks, lane L holds A[m=m16*16+(L&15)][k=ks*32+(L>>4)*8+j].
// Also zeroes the global accumulators (sum, cnt).
// ---------------------------------------------------------------------------
__global__ void qprep(const float* __restrict__ queue,
                      unsigned short* __restrict__ qs,
                      float* __restrict__ accum) {
  const int gt = blockIdx.x * 256 + threadIdx.x;  // 0..8191
  const int t = gt >> 6;
  const int lane = gt & 63;
  const int m = ((t >> 3) << 4) | (lane & 15);
  const int k0 = ((t & 7) << 5) | ((lane >> 4) << 3);
  const float* qr = queue + m * 256 + k0;
  const float TINV = 14.2857142857142857f;  // 1/0.07 folded into Q
  union { unsigned int u32[4]; uint4 v; } u;
#pragma unroll
  for (int j = 0; j < 4; ++j)
    u.u32[j] = pack_bf2(qr[2 * j] * TINV, qr[2 * j + 1] * TINV);
  *(uint4*)(qs + (size_t)gt * 8) = u.v;
  if (gt == 0) { accum[0] = 0.0f; accum[1] = 0.0f; }
}

// ---------------------------------------------------------------------------
// k1: main fused kernel. Block = 64 pixels x 256 classes, 256 threads (4 waves),
// wave w owns M rows [64w, 64w+64). Grid = 16 batches * 256 tiles = 4096 blocks.
// LDS: Bs = feats tile as bf16 in B-fragment order, tile(ks,nt) at
//      (ks*4+nt)*1024 B, frag-lane L's 16B at +L*16 (contiguous read).
// ---------------------------------------------------------------------------
__global__ __launch_bounds__(256, 4) void pcl_main(
    const float* __restrict__ feats,
    const int* __restrict__ labels,
    const unsigned short* __restrict__ qs,
    float* __restrict__ accum) {
  __shared__ uint4 Bs[2048];       // 32 KB: 32 tiles x 64 frag-slots x 16 B
  __shared__ float Red[8][64];     // 2 KB: per-wave neg/pos partials

  const int bx = blockIdx.x;
  const int bidx = bx >> 8;          // batch
  const int hw0 = (bx & 255) << 6;   // pixel tile base within batch
  const int tid = threadIdx.x;
  const int w = tid >> 6;
  const int lane = tid & 63;
  const int qd = lane >> 4;          // quad 0..3
  const int s = lane & 15;

  // ---- stage: wave w loads k-rows [64w,64w+64), lane = pixel (coalesced 256B) ----
  const float* gbase = feats + (size_t)bidx * 4194304 + (size_t)hw0;
  float f[64];
#pragma unroll
  for (int i = 0; i < 64; ++i)
    f[i] = gbase[(size_t)((w << 6) + i) * 16384 + lane];

  // pack 8 consecutive k for pixel n=lane into frag slot (kg, n):
  //   tix = (kg>>2)*4 + (n>>4), slot-lane = (kg&3)*16 + (n&15)
#pragma unroll
  for (int g = 0; g < 8; ++g) {
    uint4 u;
    u.x = pack_bf2(f[8 * g + 0], f[8 * g + 1]);
    u.y = pack_bf2(f[8 * g + 2], f[8 * g + 3]);
    u.z = pack_bf2(f[8 * g + 4], f[8 * g + 5]);
    u.w = pack_bf2(f[8 * g + 6], f[8 * g + 7]);
    const int kg = (w << 3) + g;
    Bs[(((kg >> 2) << 2) + qd) * 64 + ((kg & 3) << 4) + s] = u;
  }

  floatx4 acc[4][4];
#pragma unroll
  for (int mt = 0; mt < 4; ++mt)
#pragma unroll
    for (int nt = 0; nt < 4; ++nt)
      acc[mt][nt] = floatx4{0.0f, 0.0f, 0.0f, 0.0f};

  __syncthreads();

  // ---- K loop: 8 steps of 32; per step 4 A dwordx4 (L2-hot) + 4 ds_read_b128 + 16 MFMA ----
  const bf16x8* qfrag = (const bf16x8*)qs;
  const bf16x8* Bf = (const bf16x8*)Bs;
#pragma unroll
  for (int ks = 0; ks < 8; ++ks) {
    bf16x8 af[4];
#pragma unroll
    for (int mt = 0; mt < 4; ++mt)
      af[mt] = qfrag[(((((w << 2) + mt) << 3) | ks) << 6) + lane];
    bf16x8 bfv[4];
#pragma unroll
    for (int nt = 0; nt < 4; ++nt)
      bfv[nt] = Bf[(((ks << 2) + nt) << 6) + lane];
#pragma unroll
    for (int mt = 0; mt < 4; ++mt)
#pragma unroll
      for (int nt = 0; nt < 4; ++nt)
        acc[mt][nt] = __builtin_amdgcn_mfma_f32_16x16x32_bf16(af[mt], bfv[nt],
                                                              acc[mt][nt], 0, 0, 0);
  }

  // ---- epilogue: lane holds C[m = 64w+16mt+4qd+r][n = 16nt+s], r=0..3 ----
  // labels int4 at [pixel][64w+16mt+4qd] matches the 4 acc regs exactly.
  // Double-buffer the 4-int4 batches (32 VGPRs) to pipeline HBM label reads.
  const size_t nbase = (size_t)bx << 6;
  const int cbase = (w << 6) | (qd << 2);

  float nn[4] = {0.f, 0.f, 0.f, 0.f};
  float pp[4] = {0.f, 0.f, 0.f, 0.f};

  int4 labA[4], labB[4];
#pragma unroll
  for (int nt = 0; nt < 4; ++nt)
    labA[nt] = *(const int4*)(labels + ((nbase + (nt << 4) + s) << 8) + cbase);

#define TERM(LV, AV, NTI)                                   \
  do {                                                      \
    const bool p_ = (LV) != 0;                              \
    const float l_ = (AV);                                  \
    const float e_ = __expf(p_ ? -l_ : l_);                 \
    nn[NTI] += p_ ? 0.0f : e_;                              \
    pp[NTI] += p_ ? e_ : 0.0f;                              \
  } while (0)

#pragma unroll
  for (int mt = 0; mt < 4; ++mt) {
    const int4* cur = (mt & 1) ? labB : labA;
    int4* nxt = (mt & 1) ? labA : labB;
    if (mt < 3) {
#pragma unroll
      for (int nt = 0; nt < 4; ++nt)
        nxt[nt] = *(const int4*)(labels + ((nbase + (nt << 4) + s) << 8) +
                                 cbase + ((mt + 1) << 4));
    }
#pragma unroll
    for (int nt = 0; nt < 4; ++nt) {
      const int4 lb = cur[nt];
      const floatx4 a = acc[mt][nt];
      TERM(lb.x, a[0], nt);
      TERM(lb.y, a[1], nt);
      TERM(lb.z, a[2], nt);
      TERM(lb.w, a[3], nt);
    }
  }
#undef TERM

  // quad-reduce (lanes l, l+16, l+32, l+48 share a pixel)
#pragma unroll
  for (int nt = 0; nt < 4; ++nt) {
    nn[nt] += __shfl_xor(nn[nt], 16);
    nn[nt] += __shfl_xor(nn[nt], 32);
    pp[nt] += __shfl_xor(pp[nt], 16);
    pp[nt] += __shfl_xor(pp[nt], 32);
  }
  if (lane < 16) {
#pragma unroll
    for (int nt = 0; nt < 4; ++nt) {
      Red[(w << 1) | 0][(nt << 4) + lane] = nn[nt];
      Red[(w << 1) | 1][(nt << 4) + lane] = pp[nt];
    }
  }
  __syncthreads();

  if (tid < 64) {
    const float sn = Red[0][tid] + Red[2][tid] + Red[4][tid] + Red[6][tid];
    const float sp = Red[1][tid] + Red[3][tid] + Red[5][tid] + Red[7][tid];
    float loss = logf(sn * sp + 1.0f);
    float c = (loss != 0.0f) ? 1.0f : 0.0f;
#pragma unroll
    for (int off = 32; off > 0; off >>= 1) {
      loss += __shfl_xor(loss, off);
      c += __shfl_xor(c, off);
    }
    if (tid == 0) {
      atomicAdd(&accum[0], loss);
      atomicAdd(&accum[1], c);
    }
  }
}

// ---------------------------------------------------------------------------
// k2: scalar finalize. Mirrors where(lb_num==0, 0, sum/max(lb_num,1)).
// ---------------------------------------------------------------------------
__global__ void pcl_finalize(const float* __restrict__ accum,
                             float* __restrict__ out) {
  const float ssum = accum[0];
  const float c = accum[1];
  out[0] = (c != 0.0f) ? (ssum / c) : 0.0f;
}

extern "C" void kernel_launch(void* const* d_in, const int* in_sizes, int n_in,
                              void* d_out, int out_size, void* d_ws, size_t ws_size,
                              hipStream_t stream) {
  (void)in_sizes; (void)n_in; (void)out_size; (void)ws_size;
  const float* feats = (const float*)d_in[0];
  const float* queue = (const float*)d_in[1];
  const int* labels = (const int*)d_in[2];

  // workspace: [0,128KB) swizzled bf16 queue, [128KB, +8B) accumulators
  unsigned short* qs = (unsigned short*)d_ws;
  float* accum = (float*)((char*)d_ws + 256 * 256 * sizeof(unsigned short));

  qprep<<<32, 256, 0, stream>>>(queue, qs, accum);
  pcl_main<<<4096, 256, 0, stream>>>(feats, labels, qs, accum);
  pcl_finalize<<<1, 1, 0, stream>>>(accum, (float*)d_out);
}